// Round 8
// baseline (1944.361 us; speedup 1.0000x reference)
//
#include <hip/hip_runtime.h>
#include <hip/hip_bf16.h>
#include <math.h>

namespace {

constexpr int kB = 128, kF = 2048, kH = 1024, kE = 512, kV = 16384, kT = 20;

typedef __attribute__((ext_vector_type(4))) float f32x4;
typedef __attribute__((ext_vector_type(8))) short bf16x8;

#define MFMA(a, b, c) __builtin_amdgcn_mfma_f32_16x16x32_bf16((a), (b), (c), 0, 0, 0)

__device__ __forceinline__ short f2bf(float f) {
  union { float f; unsigned u; } un;
  un.f = f;
  unsigned x = un.u;
  x += 0x7fffu + ((x >> 16) & 1u);
  return (short)(x >> 16);
}

__device__ __forceinline__ float bf2f(short s) {
  union { unsigned u; float f; } un;
  un.u = ((unsigned)(unsigned short)s) << 16;
  return un.f;
}

__device__ __forceinline__ float sigm(float x) { return 1.0f / (1.0f + __expf(-x)); }

__device__ __forceinline__ void cvt4(const float* __restrict__ s, short* __restrict__ d,
                                     long n4, long gid, long gs) {
  for (long i = gid; i < n4; i += gs) {
    float4 v = ((const float4*)s)[i];
    short4 o;
    o.x = f2bf(v.x); o.y = f2bf(v.y); o.z = f2bf(v.z); o.w = f2bf(v.w);
    ((short4*)d)[i] = o;
  }
}

// ---------------- prologue: fp32 -> bf16 weight conversion + e0 (fp32) ----------------
__global__ __launch_bounds__(256) void k_convert(
    const float* __restrict__ wout, const float* __restrict__ emb,
    const float* __restrict__ wih, const float* __restrict__ whh,
    const float* __restrict__ aw, const float* __restrict__ img,
    const float* __restrict__ sos,
    short* __restrict__ wout_b, short* __restrict__ emb_b,
    short* __restrict__ wih_b, short* __restrict__ whh_b,
    short* __restrict__ aw_b, short* __restrict__ img_b,
    float* __restrict__ e_f) {
  long gid = (long)blockIdx.x * blockDim.x + threadIdx.x;
  long gs = (long)gridDim.x * blockDim.x;
  cvt4(wout, wout_b, (long)kV * kH / 4, gid, gs);
  cvt4(emb, emb_b, (long)kE * kV / 4, gid, gs);
  cvt4(wih, wih_b, (long)3 * kH * kE / 4, gid, gs);
  cvt4(whh, whh_b, (long)3 * kH * kH / 4, gid, gs);
  cvt4(aw, aw_b, (long)kH * kF / 4, gid, gs);
  cvt4(img, img_b, (long)kB * kF / 4, gid, gs);
  for (long i = gid; i < kB * kE; i += gs) e_f[i] = sos[i & (kE - 1)];
}

// ---------------- h0 = img @ agent_w.T + agent_b ----------------
__global__ __launch_bounds__(256) void k_h0(const short* __restrict__ img_b,
                                            const short* __restrict__ aw_b,
                                            const float* __restrict__ ab,
                                            float* __restrict__ hf, short* __restrict__ hb) {
  int tid = threadIdx.x;
  int l = tid & 63, w = tid >> 6;
  int lr = l & 15, g = l >> 4, lk = g * 8;
  int col0 = blockIdx.x * 16;
  int row0 = w * 32;
  f32x4 acc[2] = {};
#pragma unroll 4
  for (int k0 = 0; k0 < kF; k0 += 32) {
    bf16x8 a0 = *(const bf16x8*)&img_b[(row0 + lr) * kF + k0 + lk];
    bf16x8 a1 = *(const bf16x8*)&img_b[(row0 + 16 + lr) * kF + k0 + lk];
    bf16x8 b = *(const bf16x8*)&aw_b[(size_t)(col0 + lr) * kF + k0 + lk];
    acc[0] = MFMA(a0, b, acc[0]);
    acc[1] = MFMA(a1, b, acc[1]);
  }
  int col = col0 + lr;
  float bias = ab[col];
#pragma unroll
  for (int mf = 0; mf < 2; ++mf)
#pragma unroll
    for (int j = 0; j < 4; ++j) {
      int row = row0 + mf * 16 + g * 4 + j;
      float v = acc[mf][j] + bias;
      hf[row * kH + col] = v;
      hb[row * kH + col] = f2bf(v);
    }
}

// ---------------- GRU cell (512 blocks) + overlapped out-write of step t-1 ----------------
// grid 512 = colt(64) x rq(8, 16-row tiles); 256 thr, 4 waves = 4-way K-split, LDS combine.
// Prologue (all blocks): write a 16KB slice of out(t-1) = p_prev/denom_prev, NT stores.
__global__ __launch_bounds__(256) void k_gru(
    const float* __restrict__ e_f, const short* __restrict__ hb_prev,
    float* __restrict__ hf,
    const short* __restrict__ wih_b, const short* __restrict__ whh_b,
    const float* __restrict__ bih, const float* __restrict__ bhh,
    short* __restrict__ hb_next, float* __restrict__ denom_cur,
    const short* __restrict__ p_prev, const float* __restrict__ denom_prev,
    float* __restrict__ out_prev) {
  int tid = threadIdx.x, bid = blockIdx.x;
  int l = tid & 63, w = tid >> 6;
  int lr = l & 15, g = l >> 4, lk = g * 8;
  __shared__ f32x4 part[4][4][64];  // [comp][kq][lane], 16 KB
  // ---- streaming out-write of previous step (independent; overlaps weight loads) ----
  if (out_prev != nullptr) {
    int r = bid >> 2, q = bid & 3;
    float rd = 1.0f / denom_prev[r];
    int coff = q * 4096 + tid * 16;
    const short* pr = p_prev + (size_t)r * kV + coff;
    float* orow = out_prev + (size_t)r * (kT * kV) + coff;
#pragma unroll
    for (int jj = 0; jj < 2; ++jj) {
      bf16x8 p8 = *(const bf16x8*)(pr + jj * 8);
      f32x4 o0, o1;
      o0[0] = bf2f(p8[0]) * rd; o0[1] = bf2f(p8[1]) * rd;
      o0[2] = bf2f(p8[2]) * rd; o0[3] = bf2f(p8[3]) * rd;
      o1[0] = bf2f(p8[4]) * rd; o1[1] = bf2f(p8[5]) * rd;
      o1[2] = bf2f(p8[6]) * rd; o1[3] = bf2f(p8[7]) * rd;
      __builtin_nontemporal_store(o0, (f32x4*)(orow + jj * 8));
      __builtin_nontemporal_store(o1, (f32x4*)(orow + jj * 8 + 4));
    }
  }
  if (bid == 0 && tid < 32) {
    f32x4 z = {0.0f, 0.0f, 0.0f, 0.0f};
    *(f32x4*)&denom_cur[tid * 4] = z;
  }
  int colt = bid & 63, rq = bid >> 6;
  int col0 = colt * 16, row0 = rq * 16;
  int kq = w;
  f32x4 ar = {}, az = {}, ain = {}, ahn = {};
#pragma unroll
  for (int ki = 0; ki < 4; ++ki) {
    int k0 = kq * 128 + ki * 32;
    float4 af0 = *(const float4*)&e_f[(row0 + lr) * kE + k0 + lk];
    float4 af1 = *(const float4*)&e_f[(row0 + lr) * kE + k0 + lk + 4];
    bf16x8 a;
    a[0] = f2bf(af0.x); a[1] = f2bf(af0.y); a[2] = f2bf(af0.z); a[3] = f2bf(af0.w);
    a[4] = f2bf(af1.x); a[5] = f2bf(af1.y); a[6] = f2bf(af1.z); a[7] = f2bf(af1.w);
    bf16x8 br = *(const bf16x8*)&wih_b[(size_t)(col0 + lr) * kE + k0 + lk];
    bf16x8 bz = *(const bf16x8*)&wih_b[(size_t)(kH + col0 + lr) * kE + k0 + lk];
    bf16x8 bn = *(const bf16x8*)&wih_b[(size_t)(2 * kH + col0 + lr) * kE + k0 + lk];
    ar = MFMA(a, br, ar);
    az = MFMA(a, bz, az);
    ain = MFMA(a, bn, ain);
  }
#pragma unroll
  for (int ki = 0; ki < 8; ++ki) {
    int k0 = kq * 256 + ki * 32;
    bf16x8 a = *(const bf16x8*)&hb_prev[(row0 + lr) * kH + k0 + lk];
    bf16x8 br = *(const bf16x8*)&whh_b[(size_t)(col0 + lr) * kH + k0 + lk];
    bf16x8 bz = *(const bf16x8*)&whh_b[(size_t)(kH + col0 + lr) * kH + k0 + lk];
    bf16x8 bn = *(const bf16x8*)&whh_b[(size_t)(2 * kH + col0 + lr) * kH + k0 + lk];
    ar = MFMA(a, br, ar);
    az = MFMA(a, bz, az);
    ahn = MFMA(a, bn, ahn);
  }
  part[0][kq][l] = ar;
  part[1][kq][l] = az;
  part[2][kq][l] = ain;
  part[3][kq][l] = ahn;
  __syncthreads();
  if (w == 0) {
    f32x4 rs = part[0][0][l] + part[0][1][l] + part[0][2][l] + part[0][3][l];
    f32x4 zs = part[1][0][l] + part[1][1][l] + part[1][2][l] + part[1][3][l];
    f32x4 is = part[2][0][l] + part[2][1][l] + part[2][2][l] + part[2][3][l];
    f32x4 hs = part[3][0][l] + part[3][1][l] + part[3][2][l] + part[3][3][l];
    int col = col0 + lr;
    float bihr = bih[col], bhhr = bhh[col];
    float bihz = bih[kH + col], bhhz = bhh[kH + col];
    float bihn = bih[2 * kH + col], bhhn = bhh[2 * kH + col];
#pragma unroll
    for (int j = 0; j < 4; ++j) {
      int row = row0 + g * 4 + j;
      float r = sigm(rs[j] + bihr + bhhr);
      float z = sigm(zs[j] + bihz + bhhz);
      float nn = tanhf(is[j] + bihn + r * (hs[j] + bhhn));
      float hv = (1.0f - z) * nn + z * hf[row * kH + col];
      hf[row * kH + col] = hv;
      hb_next[row * kH + col] = f2bf(hv);
    }
  }
}

// ---------------- logits GEMM + p = exp(logit+gumbel) + row-sum atomics ----------------
// grid 512 (V/32 tiles), 512 thr; waves 4M x 2N (wave 32r x 16c) -> 4 waves/SIMD.
// No max subtraction: |logit+gumbel| << 88, exp() safe in fp32 (exact after division).
// Ring prefetch: B 8-deep, A 2-deep; gumbel loads nontemporal; zeroes e_f for k_e.
__global__ __launch_bounds__(512, 4) void k_logits(
    const short* __restrict__ h_b, const short* __restrict__ wout_b,
    const float* __restrict__ bout, const float* __restrict__ gum_t,
    short* __restrict__ p_b, float* __restrict__ denom, float* __restrict__ e_f) {
  int tid = threadIdx.x;
  int l = tid & 63, w = tid >> 6;
  int lr = l & 15, g = l >> 4, lk = g * 8;
  int wm = w >> 1, wn = w & 1;
  int col = blockIdx.x * 32 + wn * 16 + lr;
  int row0 = wm * 32;
  int gi = blockIdx.x * 512 + tid;
  if (gi < kB * kE) e_f[gi] = 0.0f;  // zero e accumulator for k_e atomics
  float gmr[8];
#pragma unroll
  for (int mf = 0; mf < 2; ++mf)
#pragma unroll
    for (int j = 0; j < 4; ++j)
      gmr[mf * 4 + j] = __builtin_nontemporal_load(
          &gum_t[(size_t)(row0 + mf * 16 + g * 4 + j) * kV + col]);
  float bo = bout[col];
  const short* Bp = &wout_b[(size_t)col * kH + lk];
  f32x4 acc[2] = {};
  bf16x8 brg[8], arg[2][2];
#pragma unroll
  for (int k = 0; k < 8; ++k) brg[k] = *(const bf16x8*)(Bp + k * 32);
#pragma unroll
  for (int k = 0; k < 2; ++k)
#pragma unroll
    for (int mf = 0; mf < 2; ++mf)
      arg[k][mf] = *(const bf16x8*)&h_b[(row0 + mf * 16 + lr) * kH + k * 32 + lk];
#pragma unroll
  for (int k = 0; k < 32; ++k) {
    acc[0] = MFMA(arg[k & 1][0], brg[k & 7], acc[0]);
    acc[1] = MFMA(arg[k & 1][1], brg[k & 7], acc[1]);
    if (k < 24) brg[k & 7] = *(const bf16x8*)(Bp + (k + 8) * 32);
    if (k < 30) {
#pragma unroll
      for (int mf = 0; mf < 2; ++mf)
        arg[k & 1][mf] =
            *(const bf16x8*)&h_b[(row0 + mf * 16 + lr) * kH + (k + 2) * 32 + lk];
    }
  }
  __shared__ float ls[4][2][32];
  float p[8];
#pragma unroll
  for (int i = 0; i < 8; ++i) p[i] = __expf(acc[i >> 2][i & 3] + bo + gmr[i]);
#pragma unroll
  for (int i = 0; i < 8; ++i) {
    int rl = (i >> 2) * 16 + g * 4 + (i & 3);
    p_b[(size_t)(row0 + rl) * kV + col] = f2bf(p[i]);
  }
#pragma unroll
  for (int i = 0; i < 8; ++i) {
    float s = p[i];
#pragma unroll
    for (int sf = 1; sf < 16; sf <<= 1) s += __shfl_xor(s, sf, 64);
    if (lr == 0) ls[wm][wn][(i >> 2) * 16 + g * 4 + (i & 3)] = s;
  }
  __syncthreads();
  if (tid < 128) {
    int row = tid;
    float sb = ls[row >> 5][0][row & 31] + ls[row >> 5][1][row & 31];
    atomicAdd(&denom[row], sb);
  }
}

// ---------------- e-partial GEMM: e_f += x[:, kc] @ emb[:, kc].T (atomic) ----------------
// grid 512 = kc(64 K-chunks of 256) x et(8 E-tiles of 64); 512 thr, waves 2M x 4N.
// x = p * (1/denom[row]) staged into XOR-swizzled LDS bf16.
__global__ __launch_bounds__(512, 4) void k_e(
    const short* __restrict__ p_b, const float* __restrict__ denom,
    const short* __restrict__ emb_b, float* __restrict__ e_f) {
  int tid = threadIdx.x;
  int l = tid & 63, w = tid >> 6;
  int lr = l & 15, g = l >> 4, lk = g * 8;
  int wm = w >> 2, wn = w & 3;
  int kc = blockIdx.x >> 3, et = blockIdx.x & 7;
  int kbase = kc * 256;
  int colB = et * 64 + wn * 16 + lr;
  __shared__ float s_rd[kB];
  if (tid < kB) s_rd[tid] = 1.0f / denom[tid];
  __shared__ bf16x8 xs8[2048];  // 128 rows x 128 cols bf16, XOR-swizzled
  char* xs = (char*)xs8;
  int colg = tid & 15, rrow = tid >> 4;
  f32x4 acc[4] = {};
  __syncthreads();
  for (int s = 0; s < 2; ++s) {
    if (s) __syncthreads();
#pragma unroll
    for (int rr = 0; rr < 4; ++rr) {
      int row = rr * 32 + rrow;
      int cb = s * 128 + colg * 8;
      bf16x8 p8 = *(const bf16x8*)&p_b[(size_t)row * kV + kbase + cb];
      float scl = s_rd[row];
      bf16x8 xv;
#pragma unroll
      for (int i = 0; i < 8; ++i) xv[i] = f2bf(bf2f(p8[i]) * scl);
      unsigned off = (unsigned)(row * 256 + colg * 16) ^ ((row & 7) << 4);
      *(bf16x8*)(xs + off) = xv;
    }
    __syncthreads();
#pragma unroll
    for (int kk = 0; kk < 4; ++kk) {
      bf16x8 b = *(const bf16x8*)&emb_b[(size_t)colB * kV + kbase + s * 128 + kk * 32 + lk];
#pragma unroll
      for (int mf = 0; mf < 4; ++mf) {
        int rowa = wm * 64 + mf * 16 + lr;
        unsigned off = (unsigned)(rowa * 256 + (kk * 32 + lk) * 2) ^ ((rowa & 7) << 4);
        bf16x8 a = *(const bf16x8*)(xs + off);
        acc[mf] = MFMA(a, b, acc[mf]);
      }
    }
  }
#pragma unroll
  for (int mf = 0; mf < 4; ++mf)
#pragma unroll
    for (int j = 0; j < 4; ++j) {
      int row = wm * 64 + mf * 16 + g * 4 + j;
      atomicAdd(&e_f[row * kE + et * 64 + wn * 16 + lr], acc[mf][j]);
    }
}

// ---------------- epilogue: write out for the final step ----------------
__global__ __launch_bounds__(256) void k_out(const short* __restrict__ p_b,
                                             const float* __restrict__ denom,
                                             float* __restrict__ outp) {
  int tid = threadIdx.x, bid = blockIdx.x;
  int r = bid >> 1, halfc = bid & 1;
  float rd = 1.0f / denom[r];
  int coff = halfc * 8192 + tid * 32;
  const short* pr = p_b + (size_t)r * kV + coff;
  float* orow = outp + (size_t)r * (kT * kV) + coff;
#pragma unroll
  for (int jj = 0; jj < 4; ++jj) {
    bf16x8 p8 = *(const bf16x8*)(pr + jj * 8);
    f32x4 o0, o1;
    o0[0] = bf2f(p8[0]) * rd; o0[1] = bf2f(p8[1]) * rd;
    o0[2] = bf2f(p8[2]) * rd; o0[3] = bf2f(p8[3]) * rd;
    o1[0] = bf2f(p8[4]) * rd; o1[1] = bf2f(p8[5]) * rd;
    o1[2] = bf2f(p8[6]) * rd; o1[3] = bf2f(p8[7]) * rd;
    __builtin_nontemporal_store(o0, (f32x4*)(orow + jj * 8));
    __builtin_nontemporal_store(o1, (f32x4*)(orow + jj * 8 + 4));
  }
}

}  // namespace

extern "C" void kernel_launch(void* const* d_in, const int* in_sizes, int n_in,
                              void* d_out, int out_size, void* d_ws, size_t ws_size,
                              hipStream_t stream) {
  const float* img = (const float*)d_in[0];
  const float* aw = (const float*)d_in[1];
  const float* ab = (const float*)d_in[2];
  const float* wih = (const float*)d_in[3];
  const float* whh = (const float*)d_in[4];
  const float* bih = (const float*)d_in[5];
  const float* bhh = (const float*)d_in[6];
  const float* wout = (const float*)d_in[7];
  const float* bout = (const float*)d_in[8];
  const float* emb = (const float*)d_in[9];
  const float* sos = (const float*)d_in[10];
  const float* gum = (const float*)d_in[11];
  float* out = (float*)d_out;
  char* ws = (char*)d_ws;

  short* wout_b = (short*)(ws + 0);            // 33554432
  short* emb_b = (short*)(ws + 33554432);      // 16777216
  short* wih_b = (short*)(ws + 50331648);      // 3145728
  short* whh_b = (short*)(ws + 53477376);      // 6291456
  short* aw_b = (short*)(ws + 59768832);       // 4194304
  short* img_b = (short*)(ws + 63963136);      // 524288
  float* hf = (float*)(ws + 64487424);         // 524288 (fp32 h, in-place)
  short* hb0 = (short*)(ws + 65011712);        // 262144
  short* hb1 = (short*)(ws + 65273856);        // 262144
  short* p_b = (short*)(ws + 65536000);        // 4194304
  float* denoms = (float*)(ws + 69730304);     // 2048 (2 x 256 floats)
  float* e_f = (float*)(ws + 69732352);        // 262144 (fp32 e accumulator)

  short* hb[2] = {hb0, hb1};

  k_convert<<<2048, 256, 0, stream>>>(wout, emb, wih, whh, aw, img, sos, wout_b, emb_b,
                                      wih_b, whh_b, aw_b, img_b, e_f);
  k_h0<<<64, 256, 0, stream>>>(img_b, aw_b, ab, hf, hb[0]);
  for (int t = 0; t < kT; ++t) {
    int rp = t & 1, wp = rp ^ 1;
    float* denomC = denoms + (t & 1) * 256;
    float* denomP = denoms + ((t & 1) ^ 1) * 256;
    float* out_prev = (t == 0) ? nullptr : out + (size_t)(t - 1) * kV;
    k_gru<<<512, 256, 0, stream>>>(e_f, hb[rp], hf, wih_b, whh_b, bih, bhh, hb[wp],
                                   denomC, p_b, denomP, out_prev);
    k_logits<<<512, 512, 0, stream>>>(hb[wp], wout_b, bout, gum + (size_t)t * kB * kV,
                                      p_b, denomC, e_f);
    k_e<<<512, 512, 0, stream>>>(p_b, denomC, emb_b, e_f);
  }
  k_out<<<256, 256, 0, stream>>>(p_b, denoms + 256, out + (size_t)(kT - 1) * kV);
}

// Round 9
// 1935.273 us; speedup vs baseline: 1.0047x; 1.0047x over previous
//
#include <hip/hip_runtime.h>
#include <hip/hip_bf16.h>
#include <math.h>

namespace {

constexpr int kB = 128, kF = 2048, kH = 1024, kE = 512, kV = 16384, kT = 20;

typedef __attribute__((ext_vector_type(4))) float f32x4;
typedef __attribute__((ext_vector_type(8))) short bf16x8;

#define MFMA(a, b, c) __builtin_amdgcn_mfma_f32_16x16x32_bf16((a), (b), (c), 0, 0, 0)

__device__ __forceinline__ short f2bf(float f) {
  union { float f; unsigned u; } un;
  un.f = f;
  unsigned x = un.u;
  x += 0x7fffu + ((x >> 16) & 1u);
  return (short)(x >> 16);
}

__device__ __forceinline__ float bf2f(short s) {
  union { unsigned u; float f; } un;
  un.u = ((unsigned)(unsigned short)s) << 16;
  return un.f;
}

__device__ __forceinline__ float sigm(float x) { return 1.0f / (1.0f + __expf(-x)); }

__device__ __forceinline__ void cvt4(const float* __restrict__ s, short* __restrict__ d,
                                     long n4, long gid, long gs) {
  for (long i = gid; i < n4; i += gs) {
    float4 v = ((const float4*)s)[i];
    short4 o;
    o.x = f2bf(v.x); o.y = f2bf(v.y); o.z = f2bf(v.z); o.w = f2bf(v.w);
    ((short4*)d)[i] = o;
  }
}

// ---------------- prologue: fp32 -> bf16 weight conversion + e0 (fp32) ----------------
__global__ __launch_bounds__(256) void k_convert(
    const float* __restrict__ wout, const float* __restrict__ emb,
    const float* __restrict__ wih, const float* __restrict__ whh,
    const float* __restrict__ aw, const float* __restrict__ img,
    const float* __restrict__ sos,
    short* __restrict__ wout_b, short* __restrict__ emb_b,
    short* __restrict__ wih_b, short* __restrict__ whh_b,
    short* __restrict__ aw_b, short* __restrict__ img_b,
    float* __restrict__ e_f) {
  long gid = (long)blockIdx.x * blockDim.x + threadIdx.x;
  long gs = (long)gridDim.x * blockDim.x;
  cvt4(wout, wout_b, (long)kV * kH / 4, gid, gs);
  cvt4(emb, emb_b, (long)kE * kV / 4, gid, gs);
  cvt4(wih, wih_b, (long)3 * kH * kE / 4, gid, gs);
  cvt4(whh, whh_b, (long)3 * kH * kH / 4, gid, gs);
  cvt4(aw, aw_b, (long)kH * kF / 4, gid, gs);
  cvt4(img, img_b, (long)kB * kF / 4, gid, gs);
  for (long i = gid; i < kB * kE; i += gs) e_f[i] = sos[i & (kE - 1)];
}

// ---------------- h0 = img @ agent_w.T + agent_b ----------------
__global__ __launch_bounds__(256) void k_h0(const short* __restrict__ img_b,
                                            const short* __restrict__ aw_b,
                                            const float* __restrict__ ab,
                                            float* __restrict__ hf, short* __restrict__ hb) {
  int tid = threadIdx.x;
  int l = tid & 63, w = tid >> 6;
  int lr = l & 15, g = l >> 4, lk = g * 8;
  int col0 = blockIdx.x * 16;
  int row0 = w * 32;
  f32x4 acc[2] = {};
#pragma unroll 4
  for (int k0 = 0; k0 < kF; k0 += 32) {
    bf16x8 a0 = *(const bf16x8*)&img_b[(row0 + lr) * kF + k0 + lk];
    bf16x8 a1 = *(const bf16x8*)&img_b[(row0 + 16 + lr) * kF + k0 + lk];
    bf16x8 b = *(const bf16x8*)&aw_b[(size_t)(col0 + lr) * kF + k0 + lk];
    acc[0] = MFMA(a0, b, acc[0]);
    acc[1] = MFMA(a1, b, acc[1]);
  }
  int col = col0 + lr;
  float bias = ab[col];
#pragma unroll
  for (int mf = 0; mf < 2; ++mf)
#pragma unroll
    for (int j = 0; j < 4; ++j) {
      int row = row0 + mf * 16 + g * 4 + j;
      float v = acc[mf][j] + bias;
      hf[row * kH + col] = v;
      hb[row * kH + col] = f2bf(v);
    }
}

// ---------------- GRU cell + overlapped out-write of step t-1 (R6 config) ----------------
// grid 256 = 64 col-tiles x 4 row-quarters; 512 thr.
// Waves 0-3: GRU GEMM, wave (rh, kq) = 16-row half x K-half, LDS combine.
// Waves 4-7: write out(t-1) = p_prev * (1/denom_prev) with nontemporal stores.
__global__ __launch_bounds__(512) void k_gru(
    const float* __restrict__ e_f, const short* __restrict__ hb_prev,
    float* __restrict__ hf,
    const short* __restrict__ wih_b, const short* __restrict__ whh_b,
    const float* __restrict__ bih, const float* __restrict__ bhh,
    short* __restrict__ hb_next, float* __restrict__ denom_cur,
    const short* __restrict__ p_prev, const float* __restrict__ denom_prev,
    float* __restrict__ out_prev) {
  int tid = threadIdx.x, bid = blockIdx.x;
  int l = tid & 63, w = tid >> 6;
  int lr = l & 15, g = l >> 4, lk = g * 8;
  __shared__ f32x4 part[4][2][2][64];  // [comp][rh][kq][lane], 16 KB
  int colt = bid >> 2, rq = bid & 3;
  int col0 = colt * 16;
  if (w < 4) {
    int rh = w & 1, kq = w >> 1;
    int row0 = rq * 32 + rh * 16;
    if (bid == 0 && tid < 32) {
      f32x4 z = {0.0f, 0.0f, 0.0f, 0.0f};
      *(f32x4*)&denom_cur[tid * 4] = z;
    }
    f32x4 ar = {}, az = {}, ain = {}, ahn = {};
    if (kq == 0) {
#pragma unroll 4
      for (int ki = 0; ki < 16; ++ki) {
        int k0 = ki * 32;
        float4 af0 = *(const float4*)&e_f[(row0 + lr) * kE + k0 + lk];
        float4 af1 = *(const float4*)&e_f[(row0 + lr) * kE + k0 + lk + 4];
        bf16x8 a;
        a[0] = f2bf(af0.x); a[1] = f2bf(af0.y); a[2] = f2bf(af0.z); a[3] = f2bf(af0.w);
        a[4] = f2bf(af1.x); a[5] = f2bf(af1.y); a[6] = f2bf(af1.z); a[7] = f2bf(af1.w);
        bf16x8 br = *(const bf16x8*)&wih_b[(size_t)(col0 + lr) * kE + k0 + lk];
        bf16x8 bz = *(const bf16x8*)&wih_b[(size_t)(kH + col0 + lr) * kE + k0 + lk];
        bf16x8 bn = *(const bf16x8*)&wih_b[(size_t)(2 * kH + col0 + lr) * kE + k0 + lk];
        ar = MFMA(a, br, ar);
        az = MFMA(a, bz, az);
        ain = MFMA(a, bn, ain);
      }
#pragma unroll 4
      for (int ki = 0; ki < 8; ++ki) {
        int k0 = ki * 32;
        bf16x8 a = *(const bf16x8*)&hb_prev[(row0 + lr) * kH + k0 + lk];
        bf16x8 br = *(const bf16x8*)&whh_b[(size_t)(col0 + lr) * kH + k0 + lk];
        bf16x8 bz = *(const bf16x8*)&whh_b[(size_t)(kH + col0 + lr) * kH + k0 + lk];
        bf16x8 bn = *(const bf16x8*)&whh_b[(size_t)(2 * kH + col0 + lr) * kH + k0 + lk];
        ar = MFMA(a, br, ar);
        az = MFMA(a, bz, az);
        ahn = MFMA(a, bn, ahn);
      }
    } else {
#pragma unroll 4
      for (int ki = 0; ki < 24; ++ki) {
        int k0 = 256 + ki * 32;
        bf16x8 a = *(const bf16x8*)&hb_prev[(row0 + lr) * kH + k0 + lk];
        bf16x8 br = *(const bf16x8*)&whh_b[(size_t)(col0 + lr) * kH + k0 + lk];
        bf16x8 bz = *(const bf16x8*)&whh_b[(size_t)(kH + col0 + lr) * kH + k0 + lk];
        bf16x8 bn = *(const bf16x8*)&whh_b[(size_t)(2 * kH + col0 + lr) * kH + k0 + lk];
        ar = MFMA(a, br, ar);
        az = MFMA(a, bz, az);
        ahn = MFMA(a, bn, ahn);
      }
    }
    part[0][rh][kq][l] = ar;
    part[1][rh][kq][l] = az;
    part[2][rh][kq][l] = ain;
    part[3][rh][kq][l] = ahn;
  } else if (out_prev != nullptr) {
    int r = bid >> 1, halfc = bid & 1;
    float rd = 1.0f / denom_prev[r];
    int coff = halfc * 8192 + (w - 4) * 2048 + l * 32;
    const short* pr = p_prev + (size_t)r * kV + coff;
    float* orow = out_prev + (size_t)r * (kT * kV) + coff;
#pragma unroll
    for (int jj = 0; jj < 4; ++jj) {
      bf16x8 p8 = *(const bf16x8*)(pr + jj * 8);
      f32x4 o0, o1;
      o0[0] = bf2f(p8[0]) * rd; o0[1] = bf2f(p8[1]) * rd;
      o0[2] = bf2f(p8[2]) * rd; o0[3] = bf2f(p8[3]) * rd;
      o1[0] = bf2f(p8[4]) * rd; o1[1] = bf2f(p8[5]) * rd;
      o1[2] = bf2f(p8[6]) * rd; o1[3] = bf2f(p8[7]) * rd;
      __builtin_nontemporal_store(o0, (f32x4*)(orow + jj * 8));
      __builtin_nontemporal_store(o1, (f32x4*)(orow + jj * 8 + 4));
    }
  }
  __syncthreads();
  if (w < 2) {
    int rh2 = w;
    int row0e = rq * 32 + rh2 * 16;
    f32x4 rs = part[0][rh2][0][l] + part[0][rh2][1][l];
    f32x4 zs = part[1][rh2][0][l] + part[1][rh2][1][l];
    f32x4 is = part[2][rh2][0][l] + part[2][rh2][1][l];
    f32x4 hs = part[3][rh2][0][l] + part[3][rh2][1][l];
    int col = col0 + lr;
    float bihr = bih[col], bhhr = bhh[col];
    float bihz = bih[kH + col], bhhz = bhh[kH + col];
    float bihn = bih[2 * kH + col], bhhn = bhh[2 * kH + col];
#pragma unroll
    for (int j = 0; j < 4; ++j) {
      int row = row0e + g * 4 + j;
      float r = sigm(rs[j] + bihr + bhhr);
      float z = sigm(zs[j] + bihz + bhhz);
      float nn = tanhf(is[j] + bihn + r * (hs[j] + bhhn));
      float hv = (1.0f - z) * nn + z * hf[row * kH + col];
      hf[row * kH + col] = hv;
      hb_next[row * kH + col] = f2bf(hv);
    }
  }
}

// ---------------- logits v3: LDS-staged wout + GEMM + p=exp + denom atomics ----------------
// grid 512 (V/32 tiles), 256 thr (4 waves 2M x 2N; wave = 64 rows x 16 cols).
// Stage: block's 32-row wout slice (64 KB contiguous) -> LDS, padded stride 2064 B
// (row bank-offset 4 -> conflict-free ds_read_b128). B from LDS; A 2-deep ring from L2-hot h.
__global__ __launch_bounds__(256, 2) void k_logits(
    const short* __restrict__ h_b, const short* __restrict__ wout_b,
    const float* __restrict__ bout, const float* __restrict__ gum_t,
    short* __restrict__ p_b, float* __restrict__ denom, float* __restrict__ e_f) {
  __shared__ char lds[32 * 2064];  // 66048 B
  __shared__ float ls[2][2][64];
  int tid = threadIdx.x;
  int l = tid & 63, w = tid >> 6;
  int lr = l & 15, g = l >> 4, lk = g * 8;
  int wm = w & 1, wn = w >> 1;
  int col = blockIdx.x * 32 + wn * 16 + lr;
  int mrow0 = wm * 64;
  int gi = blockIdx.x * 256 + tid;
  if (gi < kB * kE) e_f[gi] = 0.0f;  // zero e accumulator for k_e atomics (512*256 = 131072 >= 65536)
  // gumbel: issue early (T14), consume after GEMM
  float gmr[16];
#pragma unroll
  for (int mf = 0; mf < 4; ++mf)
#pragma unroll
    for (int j = 0; j < 4; ++j)
      gmr[mf * 4 + j] = __builtin_nontemporal_load(
          &gum_t[(size_t)(mrow0 + mf * 16 + g * 4 + j) * kV + col]);
  float bo = bout[col];
  // ---- stage wout slice: 32 rows x 2048 B contiguous -> LDS padded [32][2064] ----
  {
    const char* src = (const char*)(wout_b + (size_t)blockIdx.x * 32 * kH);
#pragma unroll
    for (int i = 0; i < 16; ++i) {
      int c = tid + i * 256;           // 4096 chunks of 16 B
      int row = c >> 7;
      int within = (c & 127) * 16;
      bf16x8 v = *(const bf16x8*)(src + c * 16);
      *(bf16x8*)(&lds[row * 2064 + within]) = v;
    }
  }
  __syncthreads();
  // ---- GEMM: M=128 (wave: 64), N=32 (wave: 16), K=1024, B from LDS ----
  const char* bbase = &lds[(wn * 16 + lr) * 2064 + lk * 2];
  f32x4 acc[4] = {};
  bf16x8 arg[2][4];
#pragma unroll
  for (int k = 0; k < 2; ++k)
#pragma unroll
    for (int mf = 0; mf < 4; ++mf)
      arg[k][mf] = *(const bf16x8*)&h_b[(mrow0 + mf * 16 + lr) * kH + k * 32 + lk];
#pragma unroll
  for (int k = 0; k < 32; ++k) {
    bf16x8 b = *(const bf16x8*)(bbase + k * 64);
    acc[0] = MFMA(arg[k & 1][0], b, acc[0]);
    acc[1] = MFMA(arg[k & 1][1], b, acc[1]);
    acc[2] = MFMA(arg[k & 1][2], b, acc[2]);
    acc[3] = MFMA(arg[k & 1][3], b, acc[3]);
    if (k < 30) {
#pragma unroll
      for (int mf = 0; mf < 4; ++mf)
        arg[k & 1][mf] =
            *(const bf16x8*)&h_b[(mrow0 + mf * 16 + lr) * kH + (k + 2) * 32 + lk];
    }
  }
  float p[16];
#pragma unroll
  for (int i = 0; i < 16; ++i) p[i] = __expf(acc[i >> 2][i & 3] + bo + gmr[i]);
#pragma unroll
  for (int i = 0; i < 16; ++i) {
    int rl = (i >> 2) * 16 + g * 4 + (i & 3);
    p_b[(size_t)(mrow0 + rl) * kV + col] = f2bf(p[i]);
  }
#pragma unroll
  for (int i = 0; i < 16; ++i) {
    float s = p[i];
#pragma unroll
    for (int sf = 1; sf < 16; sf <<= 1) s += __shfl_xor(s, sf, 64);
    if (lr == 0) ls[wm][wn][(i >> 2) * 16 + g * 4 + (i & 3)] = s;
  }
  __syncthreads();
  if (tid < 128) {
    int row = tid;
    float sb = ls[row >> 6][0][row & 63] + ls[row >> 6][1][row & 63];
    atomicAdd(&denom[row], sb);
  }
}

// ---------------- e-partial GEMM (R6 config): e_f += x[:, kc] @ emb[:, kc].T ----------------
// grid 256 = kc(32 K-chunks of 512) x et(8 E-tiles of 64); 512 thr, waves 2M x 4N.
// x = p * (1/denom[row]) staged into XOR-swizzled LDS bf16.
__global__ __launch_bounds__(512) void k_e(
    const short* __restrict__ p_b, const float* __restrict__ denom,
    const short* __restrict__ emb_b, float* __restrict__ e_f) {
  int tid = threadIdx.x;
  int l = tid & 63, w = tid >> 6;
  int lr = l & 15, g = l >> 4, lk = g * 8;
  int wm = w >> 2, wn = w & 3;
  int kc = blockIdx.x >> 3, et = blockIdx.x & 7;
  int kbase = kc * 512;
  int colB = et * 64 + wn * 16 + lr;
  __shared__ float s_rd[kB];
  if (tid < kB) s_rd[tid] = 1.0f / denom[tid];
  __shared__ bf16x8 xs8[2048];  // 128 rows x 128 cols bf16, XOR-swizzled
  char* xs = (char*)xs8;
  int colg = tid & 15, rrow = tid >> 4;
  f32x4 acc[4] = {};
  __syncthreads();
  for (int s = 0; s < 4; ++s) {
    if (s) __syncthreads();
#pragma unroll
    for (int rr = 0; rr < 4; ++rr) {
      int row = rr * 32 + rrow;
      int cb = s * 128 + colg * 8;
      bf16x8 p8 = *(const bf16x8*)&p_b[(size_t)row * kV + kbase + cb];
      float scl = s_rd[row];
      bf16x8 xv;
#pragma unroll
      for (int i = 0; i < 8; ++i) xv[i] = f2bf(bf2f(p8[i]) * scl);
      unsigned off = (unsigned)(row * 256 + colg * 16) ^ ((row & 7) << 4);
      *(bf16x8*)(xs + off) = xv;
    }
    __syncthreads();
#pragma unroll
    for (int kk = 0; kk < 4; ++kk) {
      bf16x8 b = *(const bf16x8*)&emb_b[(size_t)colB * kV + kbase + s * 128 + kk * 32 + lk];
#pragma unroll
      for (int mf = 0; mf < 4; ++mf) {
        int rowa = wm * 64 + mf * 16 + lr;
        unsigned off = (unsigned)(rowa * 256 + (kk * 32 + lk) * 2) ^ ((rowa & 7) << 4);
        bf16x8 a = *(const bf16x8*)(xs + off);
        acc[mf] = MFMA(a, b, acc[mf]);
      }
    }
  }
#pragma unroll
  for (int mf = 0; mf < 4; ++mf)
#pragma unroll
    for (int j = 0; j < 4; ++j) {
      int row = wm * 64 + mf * 16 + g * 4 + j;
      atomicAdd(&e_f[row * kE + et * 64 + wn * 16 + lr], acc[mf][j]);
    }
}

// ---------------- epilogue: write out for the final step ----------------
__global__ __launch_bounds__(256) void k_out(const short* __restrict__ p_b,
                                             const float* __restrict__ denom,
                                             float* __restrict__ outp) {
  int tid = threadIdx.x, bid = blockIdx.x;
  int r = bid >> 1, halfc = bid & 1;
  float rd = 1.0f / denom[r];
  int coff = halfc * 8192 + tid * 32;
  const short* pr = p_b + (size_t)r * kV + coff;
  float* orow = outp + (size_t)r * (kT * kV) + coff;
#pragma unroll
  for (int jj = 0; jj < 4; ++jj) {
    bf16x8 p8 = *(const bf16x8*)(pr + jj * 8);
    f32x4 o0, o1;
    o0[0] = bf2f(p8[0]) * rd; o0[1] = bf2f(p8[1]) * rd;
    o0[2] = bf2f(p8[2]) * rd; o0[3] = bf2f(p8[3]) * rd;
    o1[0] = bf2f(p8[4]) * rd; o1[1] = bf2f(p8[5]) * rd;
    o1[2] = bf2f(p8[6]) * rd; o1[3] = bf2f(p8[7]) * rd;
    __builtin_nontemporal_store(o0, (f32x4*)(orow + jj * 8));
    __builtin_nontemporal_store(o1, (f32x4*)(orow + jj * 8 + 4));
  }
}

}  // namespace

extern "C" void kernel_launch(void* const* d_in, const int* in_sizes, int n_in,
                              void* d_out, int out_size, void* d_ws, size_t ws_size,
                              hipStream_t stream) {
  const float* img = (const float*)d_in[0];
  const float* aw = (const float*)d_in[1];
  const float* ab = (const float*)d_in[2];
  const float* wih = (const float*)d_in[3];
  const float* whh = (const float*)d_in[4];
  const float* bih = (const float*)d_in[5];
  const float* bhh = (const float*)d_in[6];
  const float* wout = (const float*)d_in[7];
  const float* bout = (const float*)d_in[8];
  const float* emb = (const float*)d_in[9];
  const float* sos = (const float*)d_in[10];
  const float* gum = (const float*)d_in[11];
  float* out = (float*)d_out;
  char* ws = (char*)d_ws;

  short* wout_b = (short*)(ws + 0);            // 33554432
  short* emb_b = (short*)(ws + 33554432);      // 16777216
  short* wih_b = (short*)(ws + 50331648);      // 3145728
  short* whh_b = (short*)(ws + 53477376);      // 6291456
  short* aw_b = (short*)(ws + 59768832);       // 4194304
  short* img_b = (short*)(ws + 63963136);      // 524288
  float* hf = (float*)(ws + 64487424);         // 524288 (fp32 h, in-place)
  short* hb0 = (short*)(ws + 65011712);        // 262144
  short* hb1 = (short*)(ws + 65273856);        // 262144
  short* p_b = (short*)(ws + 65536000);        // 4194304
  float* denoms = (float*)(ws + 69730304);     // 2048 (2 x 256 floats)
  float* e_f = (float*)(ws + 69732352);        // 262144 (fp32 e accumulator)

  short* hb[2] = {hb0, hb1};

  k_convert<<<2048, 256, 0, stream>>>(wout, emb, wih, whh, aw, img, sos, wout_b, emb_b,
                                      wih_b, whh_b, aw_b, img_b, e_f);
  k_h0<<<64, 256, 0, stream>>>(img_b, aw_b, ab, hf, hb[0]);
  for (int t = 0; t < kT; ++t) {
    int rp = t & 1, wp = rp ^ 1;
    float* denomC = denoms + (t & 1) * 256;
    float* denomP = denoms + ((t & 1) ^ 1) * 256;
    float* out_prev = (t == 0) ? nullptr : out + (size_t)(t - 1) * kV;
    k_gru<<<256, 512, 0, stream>>>(e_f, hb[rp], hf, wih_b, whh_b, bih, bhh, hb[wp],
                                   denomC, p_b, denomP, out_prev);
    k_logits<<<512, 256, 0, stream>>>(hb[wp], wout_b, bout, gum + (size_t)t * kB * kV,
                                      p_b, denomC, e_f);
    k_e<<<256, 512, 0, stream>>>(p_b, denomC, emb_b, e_f);
  }
  k_out<<<256, 256, 0, stream>>>(p_b, denoms + 256, out + (size_t)(kT - 1) * kV);
}

// Round 11
// 1822.165 us; speedup vs baseline: 1.0671x; 1.0621x over previous
//
#include <hip/hip_runtime.h>
#include <hip/hip_bf16.h>
#include <math.h>

namespace {

constexpr int kB = 128, kF = 2048, kH = 1024, kE = 512, kV = 16384, kT = 20;

typedef __attribute__((ext_vector_type(4))) float f32x4;
typedef __attribute__((ext_vector_type(8))) short bf16x8;

#define MFMA(a, b, c) __builtin_amdgcn_mfma_f32_16x16x32_bf16((a), (b), (c), 0, 0, 0)

__device__ __forceinline__ short f2bf(float f) {
  union { float f; unsigned u; } un;
  un.f = f;
  unsigned x = un.u;
  x += 0x7fffu + ((x >> 16) & 1u);
  return (short)(x >> 16);
}

__device__ __forceinline__ float bf2f(short s) {
  union { unsigned u; float f; } un;
  un.u = ((unsigned)(unsigned short)s) << 16;
  return un.f;
}

__device__ __forceinline__ float sigm(float x) { return 1.0f / (1.0f + __expf(-x)); }

__device__ __forceinline__ void cvt4(const float* __restrict__ s, short* __restrict__ d,
                                     long n4, long gid, long gs) {
  for (long i = gid; i < n4; i += gs) {
    float4 v = ((const float4*)s)[i];
    short4 o;
    o.x = f2bf(v.x); o.y = f2bf(v.y); o.z = f2bf(v.z); o.w = f2bf(v.w);
    ((short4*)d)[i] = o;
  }
}

// ---------------- prologue: fp32 -> bf16 weight conversion + e0 (fp32) ----------------
__global__ __launch_bounds__(256) void k_convert(
    const float* __restrict__ wout, const float* __restrict__ emb,
    const float* __restrict__ wih, const float* __restrict__ whh,
    const float* __restrict__ aw, const float* __restrict__ img,
    const float* __restrict__ sos,
    short* __restrict__ wout_b, short* __restrict__ emb_b,
    short* __restrict__ wih_b, short* __restrict__ whh_b,
    short* __restrict__ aw_b, short* __restrict__ img_b,
    float* __restrict__ e_f) {
  long gid = (long)blockIdx.x * blockDim.x + threadIdx.x;
  long gs = (long)gridDim.x * blockDim.x;
  cvt4(wout, wout_b, (long)kV * kH / 4, gid, gs);
  cvt4(emb, emb_b, (long)kE * kV / 4, gid, gs);
  cvt4(wih, wih_b, (long)3 * kH * kE / 4, gid, gs);
  cvt4(whh, whh_b, (long)3 * kH * kH / 4, gid, gs);
  cvt4(aw, aw_b, (long)kH * kF / 4, gid, gs);
  cvt4(img, img_b, (long)kB * kF / 4, gid, gs);
  for (long i = gid; i < kB * kE; i += gs) e_f[i] = sos[i & (kE - 1)];
}

// ---------------- h0 = img @ agent_w.T + agent_b ----------------
__global__ __launch_bounds__(256) void k_h0(const short* __restrict__ img_b,
                                            const short* __restrict__ aw_b,
                                            const float* __restrict__ ab,
                                            float* __restrict__ hf, short* __restrict__ hb) {
  int tid = threadIdx.x;
  int l = tid & 63, w = tid >> 6;
  int lr = l & 15, g = l >> 4, lk = g * 8;
  int col0 = blockIdx.x * 16;
  int row0 = w * 32;
  f32x4 acc[2] = {};
#pragma unroll 4
  for (int k0 = 0; k0 < kF; k0 += 32) {
    bf16x8 a0 = *(const bf16x8*)&img_b[(row0 + lr) * kF + k0 + lk];
    bf16x8 a1 = *(const bf16x8*)&img_b[(row0 + 16 + lr) * kF + k0 + lk];
    bf16x8 b = *(const bf16x8*)&aw_b[(size_t)(col0 + lr) * kF + k0 + lk];
    acc[0] = MFMA(a0, b, acc[0]);
    acc[1] = MFMA(a1, b, acc[1]);
  }
  int col = col0 + lr;
  float bias = ab[col];
#pragma unroll
  for (int mf = 0; mf < 2; ++mf)
#pragma unroll
    for (int j = 0; j < 4; ++j) {
      int row = row0 + mf * 16 + g * 4 + j;
      float v = acc[mf][j] + bias;
      hf[row * kH + col] = v;
      hb[row * kH + col] = f2bf(v);
    }
}

// ---------------- GRU cell + overlapped out-write of step t-1 ----------------
// grid 256 = 64 col-tiles x 4 row-quarters; 512 thr.
// Waves 0-3: GRU GEMM (2-deep ring prefetch on strided B loads), LDS combine.
// Waves 4-7: write out(t-1) = p_prev * (1/denom_prev) with nontemporal stores.
__global__ __launch_bounds__(512) void k_gru(
    const float* __restrict__ e_f, const short* __restrict__ hb_prev,
    float* __restrict__ hf,
    const short* __restrict__ wih_b, const short* __restrict__ whh_b,
    const float* __restrict__ bih, const float* __restrict__ bhh,
    short* __restrict__ hb_next, float* __restrict__ denom_cur,
    const short* __restrict__ p_prev, const float* __restrict__ denom_prev,
    float* __restrict__ out_prev) {
  int tid = threadIdx.x, bid = blockIdx.x;
  int l = tid & 63, w = tid >> 6;
  int lr = l & 15, g = l >> 4, lk = g * 8;
  __shared__ f32x4 part[4][2][2][64];  // [comp][rh][kq][lane], 16 KB
  int colt = bid >> 2, rq = bid & 3;
  int col0 = colt * 16;
  if (w < 4) {
    int rh = w & 1, kq = w >> 1;
    int row0 = rq * 32 + rh * 16;
    if (bid == 0 && tid < 32) {
      f32x4 z = {0.0f, 0.0f, 0.0f, 0.0f};
      *(f32x4*)&denom_cur[tid * 4] = z;
    }
    f32x4 ar = {}, az = {}, ain = {}, ahn = {};
    const short* wrp = &wih_b[(size_t)(col0 + lr) * kE + lk];
    const short* wzp = &wih_b[(size_t)(kH + col0 + lr) * kE + lk];
    const short* wnp = &wih_b[(size_t)(2 * kH + col0 + lr) * kE + lk];
    const short* hrp = &whh_b[(size_t)(col0 + lr) * kH + lk];
    const short* hzp = &whh_b[(size_t)(kH + col0 + lr) * kH + lk];
    const short* hnp = &whh_b[(size_t)(2 * kH + col0 + lr) * kH + lk];
    if (kq == 0) {
      // ---- e @ wih^T over full K=512, 16 iters, 2-deep B ring ----
      bf16x8 rr[2], rz[2], rn[2];
#pragma unroll
      for (int k = 0; k < 2; ++k) {
        rr[k] = *(const bf16x8*)(wrp + k * 32);
        rz[k] = *(const bf16x8*)(wzp + k * 32);
        rn[k] = *(const bf16x8*)(wnp + k * 32);
      }
#pragma unroll
      for (int ki = 0; ki < 16; ++ki) {
        int k0 = ki * 32;
        float4 af0 = *(const float4*)&e_f[(row0 + lr) * kE + k0 + lk];
        float4 af1 = *(const float4*)&e_f[(row0 + lr) * kE + k0 + lk + 4];
        bf16x8 a;
        a[0] = f2bf(af0.x); a[1] = f2bf(af0.y); a[2] = f2bf(af0.z); a[3] = f2bf(af0.w);
        a[4] = f2bf(af1.x); a[5] = f2bf(af1.y); a[6] = f2bf(af1.z); a[7] = f2bf(af1.w);
        ar = MFMA(a, rr[ki & 1], ar);
        az = MFMA(a, rz[ki & 1], az);
        ain = MFMA(a, rn[ki & 1], ain);
        if (ki < 14) {
          rr[ki & 1] = *(const bf16x8*)(wrp + (ki + 2) * 32);
          rz[ki & 1] = *(const bf16x8*)(wzp + (ki + 2) * 32);
          rn[ki & 1] = *(const bf16x8*)(wnp + (ki + 2) * 32);
        }
      }
      // ---- h @ whh^T K-quarter [0,256), 8 iters ----
      bf16x8 hr[2], hz[2], hn[2];
#pragma unroll
      for (int k = 0; k < 2; ++k) {
        hr[k] = *(const bf16x8*)(hrp + k * 32);
        hz[k] = *(const bf16x8*)(hzp + k * 32);
        hn[k] = *(const bf16x8*)(hnp + k * 32);
      }
#pragma unroll
      for (int ki = 0; ki < 8; ++ki) {
        int k0 = ki * 32;
        bf16x8 a = *(const bf16x8*)&hb_prev[(row0 + lr) * kH + k0 + lk];
        ar = MFMA(a, hr[ki & 1], ar);
        az = MFMA(a, hz[ki & 1], az);
        ahn = MFMA(a, hn[ki & 1], ahn);
        if (ki < 6) {
          hr[ki & 1] = *(const bf16x8*)(hrp + (ki + 2) * 32);
          hz[ki & 1] = *(const bf16x8*)(hzp + (ki + 2) * 32);
          hn[ki & 1] = *(const bf16x8*)(hnp + (ki + 2) * 32);
        }
      }
    } else {
      // ---- h @ whh^T K-range [256,1024), 24 iters, 2-deep ring ----
      bf16x8 hr[2], hz[2], hn[2];
#pragma unroll
      for (int k = 0; k < 2; ++k) {
        hr[k] = *(const bf16x8*)(hrp + (8 + k) * 32);
        hz[k] = *(const bf16x8*)(hzp + (8 + k) * 32);
        hn[k] = *(const bf16x8*)(hnp + (8 + k) * 32);
      }
#pragma unroll
      for (int ki = 0; ki < 24; ++ki) {
        int k0 = 256 + ki * 32;
        bf16x8 a = *(const bf16x8*)&hb_prev[(row0 + lr) * kH + k0 + lk];
        ar = MFMA(a, hr[ki & 1], ar);
        az = MFMA(a, hz[ki & 1], az);
        ahn = MFMA(a, hn[ki & 1], ahn);
        if (ki < 22) {
          hr[ki & 1] = *(const bf16x8*)(hrp + (ki + 10) * 32);
          hz[ki & 1] = *(const bf16x8*)(hzp + (ki + 10) * 32);
          hn[ki & 1] = *(const bf16x8*)(hnp + (ki + 10) * 32);
        }
      }
    }
    part[0][rh][kq][l] = ar;
    part[1][rh][kq][l] = az;
    part[2][rh][kq][l] = ain;
    part[3][rh][kq][l] = ahn;
  } else if (out_prev != nullptr) {
    int r = bid >> 1, halfc = bid & 1;
    float rd = 1.0f / denom_prev[r];
    int coff = halfc * 8192 + (w - 4) * 2048 + l * 32;
    const short* pr = p_prev + (size_t)r * kV + coff;
    float* orow = out_prev + (size_t)r * (kT * kV) + coff;
#pragma unroll
    for (int jj = 0; jj < 4; ++jj) {
      bf16x8 p8 = *(const bf16x8*)(pr + jj * 8);
      f32x4 o0, o1;
      o0[0] = bf2f(p8[0]) * rd; o0[1] = bf2f(p8[1]) * rd;
      o0[2] = bf2f(p8[2]) * rd; o0[3] = bf2f(p8[3]) * rd;
      o1[0] = bf2f(p8[4]) * rd; o1[1] = bf2f(p8[5]) * rd;
      o1[2] = bf2f(p8[6]) * rd; o1[3] = bf2f(p8[7]) * rd;
      __builtin_nontemporal_store(o0, (f32x4*)(orow + jj * 8));
      __builtin_nontemporal_store(o1, (f32x4*)(orow + jj * 8 + 4));
    }
  }
  __syncthreads();
  if (w < 2) {
    int rh2 = w;
    int row0e = rq * 32 + rh2 * 16;
    f32x4 rs = part[0][rh2][0][l] + part[0][rh2][1][l];
    f32x4 zs = part[1][rh2][0][l] + part[1][rh2][1][l];
    f32x4 is = part[2][rh2][0][l] + part[2][rh2][1][l];
    f32x4 hs = part[3][rh2][0][l] + part[3][rh2][1][l];
    int col = col0 + lr;
    float bihr = bih[col], bhhr = bhh[col];
    float bihz = bih[kH + col], bhhz = bhh[kH + col];
    float bihn = bih[2 * kH + col], bhhn = bhh[2 * kH + col];
#pragma unroll
    for (int j = 0; j < 4; ++j) {
      int row = row0e + g * 4 + j;
      float r = sigm(rs[j] + bihr + bhhr);
      float z = sigm(zs[j] + bihz + bhhz);
      float nn = tanhf(is[j] + bihn + r * (hs[j] + bhhn));
      float hv = (1.0f - z) * nn + z * hf[row * kH + col];
      hf[row * kH + col] = hv;
      hb_next[row * kH + col] = f2bf(hv);
    }
  }
}

// ---------------- logits v3 (R9): LDS-staged wout + GEMM + p=exp + denom atomics ----------------
// grid 512 (V/32 tiles), 256 thr (4 waves 2M x 2N; wave = 64 rows x 16 cols).
__global__ __launch_bounds__(256, 2) void k_logits(
    const short* __restrict__ h_b, const short* __restrict__ wout_b,
    const float* __restrict__ bout, const float* __restrict__ gum_t,
    short* __restrict__ p_b, float* __restrict__ denom, float* __restrict__ e_f) {
  __shared__ char lds[32 * 2064];  // 66048 B
  __shared__ float ls[2][2][64];
  int tid = threadIdx.x;
  int l = tid & 63, w = tid >> 6;
  int lr = l & 15, g = l >> 4, lk = g * 8;
  int wm = w & 1, wn = w >> 1;
  int col = blockIdx.x * 32 + wn * 16 + lr;
  int mrow0 = wm * 64;
  int gi = blockIdx.x * 256 + tid;
  if (gi < kB * kE) e_f[gi] = 0.0f;  // zero e accumulator for k_e atomics
  float gmr[16];
#pragma unroll
  for (int mf = 0; mf < 4; ++mf)
#pragma unroll
    for (int j = 0; j < 4; ++j)
      gmr[mf * 4 + j] = __builtin_nontemporal_load(
          &gum_t[(size_t)(mrow0 + mf * 16 + g * 4 + j) * kV + col]);
  float bo = bout[col];
  {
    const char* src = (const char*)(wout_b + (size_t)blockIdx.x * 32 * kH);
#pragma unroll
    for (int i = 0; i < 16; ++i) {
      int c = tid + i * 256;           // 4096 chunks of 16 B
      int row = c >> 7;
      int within = (c & 127) * 16;
      bf16x8 v = *(const bf16x8*)(src + c * 16);
      *(bf16x8*)(&lds[row * 2064 + within]) = v;
    }
  }
  __syncthreads();
  const char* bbase = &lds[(wn * 16 + lr) * 2064 + lk * 2];
  f32x4 acc[4] = {};
  bf16x8 arg[2][4];
#pragma unroll
  for (int k = 0; k < 2; ++k)
#pragma unroll
    for (int mf = 0; mf < 4; ++mf)
      arg[k][mf] = *(const bf16x8*)&h_b[(mrow0 + mf * 16 + lr) * kH + k * 32 + lk];
#pragma unroll
  for (int k = 0; k < 32; ++k) {
    bf16x8 b = *(const bf16x8*)(bbase + k * 64);
    acc[0] = MFMA(arg[k & 1][0], b, acc[0]);
    acc[1] = MFMA(arg[k & 1][1], b, acc[1]);
    acc[2] = MFMA(arg[k & 1][2], b, acc[2]);
    acc[3] = MFMA(arg[k & 1][3], b, acc[3]);
    if (k < 30) {
#pragma unroll
      for (int mf = 0; mf < 4; ++mf)
        arg[k & 1][mf] =
            *(const bf16x8*)&h_b[(mrow0 + mf * 16 + lr) * kH + (k + 2) * 32 + lk];
    }
  }
  float p[16];
#pragma unroll
  for (int i = 0; i < 16; ++i) p[i] = __expf(acc[i >> 2][i & 3] + bo + gmr[i]);
#pragma unroll
  for (int i = 0; i < 16; ++i) {
    int rl = (i >> 2) * 16 + g * 4 + (i & 3);
    p_b[(size_t)(mrow0 + rl) * kV + col] = f2bf(p[i]);
  }
#pragma unroll
  for (int i = 0; i < 16; ++i) {
    float s = p[i];
#pragma unroll
    for (int sf = 1; sf < 16; sf <<= 1) s += __shfl_xor(s, sf, 64);
    if (lr == 0) ls[wm][wn][(i >> 2) * 16 + g * 4 + (i & 3)] = s;
  }
  __syncthreads();
  if (tid < 128) {
    int row = tid;
    float sb = ls[row >> 6][0][row & 63] + ls[row >> 6][1][row & 63];
    atomicAdd(&denom[row], sb);
  }
}

// ---------------- e-partial GEMM v3: e_f += x[:, kc] @ emb[:, kc].T (atomic) ----------------
// grid 256 = kc(32 K-chunks of 512) x et(8 E-tiles of 64); 512 thr, waves 2M x 4N.
// emb slice staged to LDS double-buffered per 128-col substep (coalesced row-contiguous
// copies replace 16-line strided gathers); p loads hoisted before MFMA (issue-early).
__global__ __launch_bounds__(512) void k_e(
    const short* __restrict__ p_b, const float* __restrict__ denom,
    const short* __restrict__ emb_b, float* __restrict__ e_f) {
  int tid = threadIdx.x;
  int l = tid & 63, w = tid >> 6;
  int lr = l & 15, g = l >> 4, lk = g * 8;
  int wm = w >> 2, wn = w & 3;
  int kc = blockIdx.x >> 3, et = blockIdx.x & 7;
  int kbase = kc * 512;
  __shared__ float s_rd[kB];
  __shared__ bf16x8 xs8[2048];      // 128 rows x 128 cols bf16, XOR-swizzled (32 KB)
  __shared__ char es[2][64 * 264];  // emb substep buffers, 2 x 16.5 KB
  char* xs = (char*)xs8;
  if (tid < kB) s_rd[tid] = 1.0f / denom[tid];
  __syncthreads();  // s_rd visible to all before prologue staging reads it
  int colg = tid & 15, rrow = tid >> 4;
  // emb stage indexing: 1024 chunks of 16B per substep; thread handles 2
  int ec0 = tid * 2, ec1 = tid * 2 + 1;
  int er0 = ec0 >> 4, ew0 = (ec0 & 15) * 16;
  int er1 = ec1 >> 4, ew1 = (ec1 & 15) * 16;
  const char* esrc0 = (const char*)&emb_b[(size_t)(et * 64 + er0) * kV + kbase] + ew0;
  const char* esrc1 = (const char*)&emb_b[(size_t)(et * 64 + er1) * kV + kbase] + ew1;
  // prologue: stage emb(0) + p(0)
  {
    bf16x8 e0 = *(const bf16x8*)esrc0;
    bf16x8 e1 = *(const bf16x8*)esrc1;
    *(bf16x8*)&es[0][er0 * 264 + ew0] = e0;
    *(bf16x8*)&es[0][er1 * 264 + ew1] = e1;
#pragma unroll
    for (int rr = 0; rr < 4; ++rr) {
      int row = rr * 32 + rrow;
      bf16x8 p8 = *(const bf16x8*)&p_b[(size_t)row * kV + kbase + colg * 8];
      float scl = s_rd[row];
      bf16x8 xv;
#pragma unroll
      for (int i = 0; i < 8; ++i) xv[i] = f2bf(bf2f(p8[i]) * scl);
      unsigned off = (unsigned)(row * 256 + colg * 16) ^ ((row & 7) << 4);
      *(bf16x8*)(xs + off) = xv;
    }
  }
  __syncthreads();
  f32x4 acc[4] = {};
  int ebrow = wn * 16 + lr;
  for (int s = 0; s < 4; ++s) {
    int cur = s & 1;
    // issue next-substep loads early (land during MFMA below)
    bf16x8 ne0, ne1, np[4];
    if (s < 3) {
      ne0 = *(const bf16x8*)(esrc0 + (s + 1) * 256);
      ne1 = *(const bf16x8*)(esrc1 + (s + 1) * 256);
#pragma unroll
      for (int rr = 0; rr < 4; ++rr) {
        int row = rr * 32 + rrow;
        np[rr] = *(const bf16x8*)&p_b[(size_t)row * kV + kbase + (s + 1) * 128 + colg * 8];
      }
    }
    // MFMA substep s: B from es[cur], A from xs
#pragma unroll
    for (int kk = 0; kk < 4; ++kk) {
      bf16x8 b = *(const bf16x8*)&es[cur][ebrow * 264 + kk * 64 + lk * 2];
#pragma unroll
      for (int mf = 0; mf < 4; ++mf) {
        int rowa = wm * 64 + mf * 16 + lr;
        unsigned off = (unsigned)(rowa * 256 + (kk * 32 + lk) * 2) ^ ((rowa & 7) << 4);
        bf16x8 a = *(const bf16x8*)(xs + off);
        acc[mf] = MFMA(a, b, acc[mf]);
      }
    }
    if (s < 3) {
      __syncthreads();  // everyone done reading xs / es[cur] this round
      *(bf16x8*)&es[cur ^ 1][er0 * 264 + ew0] = ne0;
      *(bf16x8*)&es[cur ^ 1][er1 * 264 + ew1] = ne1;
#pragma unroll
      for (int rr = 0; rr < 4; ++rr) {
        int row = rr * 32 + rrow;
        float scl = s_rd[row];
        bf16x8 xv;
#pragma unroll
        for (int i = 0; i < 8; ++i) xv[i] = f2bf(bf2f(np[rr][i]) * scl);
        unsigned off = (unsigned)(row * 256 + colg * 16) ^ ((row & 7) << 4);
        *(bf16x8*)(xs + off) = xv;
      }
      __syncthreads();
    }
  }
#pragma unroll
  for (int mf = 0; mf < 4; ++mf)
#pragma unroll
    for (int j = 0; j < 4; ++j) {
      int row = wm * 64 + mf * 16 + g * 4 + j;
      atomicAdd(&e_f[row * kE + et * 64 + wn * 16 + lr], acc[mf][j]);
    }
}

// ---------------- epilogue: write out for the final step ----------------
__global__ __launch_bounds__(256) void k_out(const short* __restrict__ p_b,
                                             const float* __restrict__ denom,
                                             float* __restrict__ outp) {
  int tid = threadIdx.x, bid = blockIdx.x;
  int r = bid >> 1, halfc = bid & 1;
  float rd = 1.0f / denom[r];
  int coff = halfc * 8192 + tid * 32;
  const short* pr = p_b + (size_t)r * kV + coff;
  float* orow = outp + (size_t)r * (kT * kV) + coff;
#pragma unroll
  for (int jj = 0; jj < 4; ++jj) {
    bf16x8 p8 = *(const bf16x8*)(pr + jj * 8);
    f32x4 o0, o1;
    o0[0] = bf2f(p8[0]) * rd; o0[1] = bf2f(p8[1]) * rd;
    o0[2] = bf2f(p8[2]) * rd; o0[3] = bf2f(p8[3]) * rd;
    o1[0] = bf2f(p8[4]) * rd; o1[1] = bf2f(p8[5]) * rd;
    o1[2] = bf2f(p8[6]) * rd; o1[3] = bf2f(p8[7]) * rd;
    __builtin_nontemporal_store(o0, (f32x4*)(orow + jj * 8));
    __builtin_nontemporal_store(o1, (f32x4*)(orow + jj * 8 + 4));
  }
}

}  // namespace

extern "C" void kernel_launch(void* const* d_in, const int* in_sizes, int n_in,
                              void* d_out, int out_size, void* d_ws, size_t ws_size,
                              hipStream_t stream) {
  const float* img = (const float*)d_in[0];
  const float* aw = (const float*)d_in[1];
  const float* ab = (const float*)d_in[2];
  const float* wih = (const float*)d_in[3];
  const float* whh = (const float*)d_in[4];
  const float* bih = (const float*)d_in[5];
  const float* bhh = (const float*)d_in[6];
  const float* wout = (const float*)d_in[7];
  const float* bout = (const float*)d_in[8];
  const float* emb = (const float*)d_in[9];
  const float* sos = (const float*)d_in[10];
  const float* gum = (const float*)d_in[11];
  float* out = (float*)d_out;
  char* ws = (char*)d_ws;

  short* wout_b = (short*)(ws + 0);            // 33554432
  short* emb_b = (short*)(ws + 33554432);      // 16777216
  short* wih_b = (short*)(ws + 50331648);      // 3145728
  short* whh_b = (short*)(ws + 53477376);      // 6291456
  short* aw_b = (short*)(ws + 59768832);       // 4194304
  short* img_b = (short*)(ws + 63963136);      // 524288
  float* hf = (float*)(ws + 64487424);         // 524288 (fp32 h, in-place)
  short* hb0 = (short*)(ws + 65011712);        // 262144
  short* hb1 = (short*)(ws + 65273856);        // 262144
  short* p_b = (short*)(ws + 65536000);        // 4194304
  float* denoms = (float*)(ws + 69730304);     // 2048 (2 x 256 floats)
  float* e_f = (float*)(ws + 69732352);        // 262144 (fp32 e accumulator)

  short* hb[2] = {hb0, hb1};

  k_convert<<<2048, 256, 0, stream>>>(wout, emb, wih, whh, aw, img, sos, wout_b, emb_b,
                                      wih_b, whh_b, aw_b, img_b, e_f);
  k_h0<<<64, 256, 0, stream>>>(img_b, aw_b, ab, hf, hb[0]);
  for (int t = 0; t < kT; ++t) {
    int rp = t & 1, wp = rp ^ 1;
    float* denomC = denoms + (t & 1) * 256;
    float* denomP = denoms + ((t & 1) ^ 1) * 256;
    float* out_prev = (t == 0) ? nullptr : out + (size_t)(t - 1) * kV;
    k_gru<<<256, 512, 0, stream>>>(e_f, hb[rp], hf, wih_b, whh_b, bih, bhh, hb[wp],
                                   denomC, p_b, denomP, out_prev);
    k_logits<<<512, 256, 0, stream>>>(hb[wp], wout_b, bout, gum + (size_t)t * kB * kV,
                                      p_b, denomC, e_f);
    k_e<<<256, 512, 0, stream>>>(p_b, denomC, emb_b, e_f);
  }
  k_out<<<256, 256, 0, stream>>>(p_b, denoms + 256, out + (size_t)(kT - 1) * kV);
}

// Round 12
// 1721.826 us; speedup vs baseline: 1.1292x; 1.0583x over previous
//
#include <hip/hip_runtime.h>
#include <hip/hip_bf16.h>
#include <math.h>

namespace {

constexpr int kB = 128, kF = 2048, kH = 1024, kE = 512, kV = 16384, kT = 20;

typedef __attribute__((ext_vector_type(4))) float f32x4;
typedef __attribute__((ext_vector_type(8))) short bf16x8;

#define MFMA(a, b, c) __builtin_amdgcn_mfma_f32_16x16x32_bf16((a), (b), (c), 0, 0, 0)

__device__ __forceinline__ short f2bf(float f) {
  union { float f; unsigned u; } un;
  un.f = f;
  unsigned x = un.u;
  x += 0x7fffu + ((x >> 16) & 1u);
  return (short)(x >> 16);
}

__device__ __forceinline__ float bf2f(short s) {
  union { unsigned u; float f; } un;
  un.u = ((unsigned)(unsigned short)s) << 16;
  return un.f;
}

__device__ __forceinline__ float sigm(float x) { return 1.0f / (1.0f + __expf(-x)); }

__device__ __forceinline__ void cvt4(const float* __restrict__ s, short* __restrict__ d,
                                     long n4, long gid, long gs) {
  for (long i = gid; i < n4; i += gs) {
    float4 v = ((const float4*)s)[i];
    short4 o;
    o.x = f2bf(v.x); o.y = f2bf(v.y); o.z = f2bf(v.z); o.w = f2bf(v.w);
    ((short4*)d)[i] = o;
  }
}

// ---------------- prologue: fp32 -> bf16 weight conversion + e0 (fp32) ----------------
__global__ __launch_bounds__(256) void k_convert(
    const float* __restrict__ wout, const float* __restrict__ emb,
    const float* __restrict__ wih, const float* __restrict__ whh,
    const float* __restrict__ aw, const float* __restrict__ img,
    const float* __restrict__ sos,
    short* __restrict__ wout_b, short* __restrict__ emb_b,
    short* __restrict__ wih_b, short* __restrict__ whh_b,
    short* __restrict__ aw_b, short* __restrict__ img_b,
    float* __restrict__ e_f) {
  long gid = (long)blockIdx.x * blockDim.x + threadIdx.x;
  long gs = (long)gridDim.x * blockDim.x;
  cvt4(wout, wout_b, (long)kV * kH / 4, gid, gs);
  cvt4(emb, emb_b, (long)kE * kV / 4, gid, gs);
  cvt4(wih, wih_b, (long)3 * kH * kE / 4, gid, gs);
  cvt4(whh, whh_b, (long)3 * kH * kH / 4, gid, gs);
  cvt4(aw, aw_b, (long)kH * kF / 4, gid, gs);
  cvt4(img, img_b, (long)kB * kF / 4, gid, gs);
  for (long i = gid; i < kB * kE; i += gs) e_f[i] = sos[i & (kE - 1)];
}

// ---------------- h0 = img @ agent_w.T + agent_b ----------------
__global__ __launch_bounds__(256) void k_h0(const short* __restrict__ img_b,
                                            const short* __restrict__ aw_b,
                                            const float* __restrict__ ab,
                                            float* __restrict__ hf, short* __restrict__ hb) {
  int tid = threadIdx.x;
  int l = tid & 63, w = tid >> 6;
  int lr = l & 15, g = l >> 4, lk = g * 8;
  int col0 = blockIdx.x * 16;
  int row0 = w * 32;
  f32x4 acc[2] = {};
#pragma unroll 4
  for (int k0 = 0; k0 < kF; k0 += 32) {
    bf16x8 a0 = *(const bf16x8*)&img_b[(row0 + lr) * kF + k0 + lk];
    bf16x8 a1 = *(const bf16x8*)&img_b[(row0 + 16 + lr) * kF + k0 + lk];
    bf16x8 b = *(const bf16x8*)&aw_b[(size_t)(col0 + lr) * kF + k0 + lk];
    acc[0] = MFMA(a0, b, acc[0]);
    acc[1] = MFMA(a1, b, acc[1]);
  }
  int col = col0 + lr;
  float bias = ab[col];
#pragma unroll
  for (int mf = 0; mf < 2; ++mf)
#pragma unroll
    for (int j = 0; j < 4; ++j) {
      int row = row0 + mf * 16 + g * 4 + j;
      float v = acc[mf][j] + bias;
      hf[row * kH + col] = v;
      hb[row * kH + col] = f2bf(v);
    }
}

// ---------------- GRU cell + overlapped out-write of step t-1 ----------------
// grid 256 = 64 col-tiles x 4 row-quarters; 512 thr.
// Waves 0-3: GRU GEMM (2-deep ring prefetch on strided B loads), LDS combine.
// Waves 4-7: write out(t-1) = p_prev * (1/denom_prev) with nontemporal stores.
__global__ __launch_bounds__(512) void k_gru(
    const float* __restrict__ e_f, const short* __restrict__ hb_prev,
    float* __restrict__ hf,
    const short* __restrict__ wih_b, const short* __restrict__ whh_b,
    const float* __restrict__ bih, const float* __restrict__ bhh,
    short* __restrict__ hb_next, float* __restrict__ denom_cur,
    const short* __restrict__ p_prev, const float* __restrict__ denom_prev,
    float* __restrict__ out_prev) {
  int tid = threadIdx.x, bid = blockIdx.x;
  int l = tid & 63, w = tid >> 6;
  int lr = l & 15, g = l >> 4, lk = g * 8;
  __shared__ f32x4 part[4][2][2][64];  // [comp][rh][kq][lane], 16 KB
  int colt = bid >> 2, rq = bid & 3;
  int col0 = colt * 16;
  if (w < 4) {
    int rh = w & 1, kq = w >> 1;
    int row0 = rq * 32 + rh * 16;
    if (bid == 0 && tid < 32) {
      f32x4 z = {0.0f, 0.0f, 0.0f, 0.0f};
      *(f32x4*)&denom_cur[tid * 4] = z;
    }
    f32x4 ar = {}, az = {}, ain = {}, ahn = {};
    const short* wrp = &wih_b[(size_t)(col0 + lr) * kE + lk];
    const short* wzp = &wih_b[(size_t)(kH + col0 + lr) * kE + lk];
    const short* wnp = &wih_b[(size_t)(2 * kH + col0 + lr) * kE + lk];
    const short* hrp = &whh_b[(size_t)(col0 + lr) * kH + lk];
    const short* hzp = &whh_b[(size_t)(kH + col0 + lr) * kH + lk];
    const short* hnp = &whh_b[(size_t)(2 * kH + col0 + lr) * kH + lk];
    if (kq == 0) {
      // ---- e @ wih^T over full K=512, 16 iters, 2-deep B ring ----
      bf16x8 rr[2], rz[2], rn[2];
#pragma unroll
      for (int k = 0; k < 2; ++k) {
        rr[k] = *(const bf16x8*)(wrp + k * 32);
        rz[k] = *(const bf16x8*)(wzp + k * 32);
        rn[k] = *(const bf16x8*)(wnp + k * 32);
      }
#pragma unroll
      for (int ki = 0; ki < 16; ++ki) {
        int k0 = ki * 32;
        float4 af0 = *(const float4*)&e_f[(row0 + lr) * kE + k0 + lk];
        float4 af1 = *(const float4*)&e_f[(row0 + lr) * kE + k0 + lk + 4];
        bf16x8 a;
        a[0] = f2bf(af0.x); a[1] = f2bf(af0.y); a[2] = f2bf(af0.z); a[3] = f2bf(af0.w);
        a[4] = f2bf(af1.x); a[5] = f2bf(af1.y); a[6] = f2bf(af1.z); a[7] = f2bf(af1.w);
        ar = MFMA(a, rr[ki & 1], ar);
        az = MFMA(a, rz[ki & 1], az);
        ain = MFMA(a, rn[ki & 1], ain);
        if (ki < 14) {
          rr[ki & 1] = *(const bf16x8*)(wrp + (ki + 2) * 32);
          rz[ki & 1] = *(const bf16x8*)(wzp + (ki + 2) * 32);
          rn[ki & 1] = *(const bf16x8*)(wnp + (ki + 2) * 32);
        }
      }
      // ---- h @ whh^T K-quarter [0,256), 8 iters ----
      bf16x8 hr[2], hz[2], hn[2];
#pragma unroll
      for (int k = 0; k < 2; ++k) {
        hr[k] = *(const bf16x8*)(hrp + k * 32);
        hz[k] = *(const bf16x8*)(hzp + k * 32);
        hn[k] = *(const bf16x8*)(hnp + k * 32);
      }
#pragma unroll
      for (int ki = 0; ki < 8; ++ki) {
        int k0 = ki * 32;
        bf16x8 a = *(const bf16x8*)&hb_prev[(row0 + lr) * kH + k0 + lk];
        ar = MFMA(a, hr[ki & 1], ar);
        az = MFMA(a, hz[ki & 1], az);
        ahn = MFMA(a, hn[ki & 1], ahn);
        if (ki < 6) {
          hr[ki & 1] = *(const bf16x8*)(hrp + (ki + 2) * 32);
          hz[ki & 1] = *(const bf16x8*)(hzp + (ki + 2) * 32);
          hn[ki & 1] = *(const bf16x8*)(hnp + (ki + 2) * 32);
        }
      }
    } else {
      // ---- h @ whh^T K-range [256,1024), 24 iters, 2-deep ring ----
      bf16x8 hr[2], hz[2], hn[2];
#pragma unroll
      for (int k = 0; k < 2; ++k) {
        hr[k] = *(const bf16x8*)(hrp + (8 + k) * 32);
        hz[k] = *(const bf16x8*)(hzp + (8 + k) * 32);
        hn[k] = *(const bf16x8*)(hnp + (8 + k) * 32);
      }
#pragma unroll
      for (int ki = 0; ki < 24; ++ki) {
        int k0 = 256 + ki * 32;
        bf16x8 a = *(const bf16x8*)&hb_prev[(row0 + lr) * kH + k0 + lk];
        ar = MFMA(a, hr[ki & 1], ar);
        az = MFMA(a, hz[ki & 1], az);
        ahn = MFMA(a, hn[ki & 1], ahn);
        if (ki < 22) {
          hr[ki & 1] = *(const bf16x8*)(hrp + (ki + 10) * 32);
          hz[ki & 1] = *(const bf16x8*)(hzp + (ki + 10) * 32);
          hn[ki & 1] = *(const bf16x8*)(hnp + (ki + 10) * 32);
        }
      }
    }
    part[0][rh][kq][l] = ar;
    part[1][rh][kq][l] = az;
    part[2][rh][kq][l] = ain;
    part[3][rh][kq][l] = ahn;
  } else if (out_prev != nullptr) {
    int r = bid >> 1, halfc = bid & 1;
    float rd = 1.0f / denom_prev[r];
    int coff = halfc * 8192 + (w - 4) * 2048 + l * 32;
    const short* pr = p_prev + (size_t)r * kV + coff;
    float* orow = out_prev + (size_t)r * (kT * kV) + coff;
#pragma unroll
    for (int jj = 0; jj < 4; ++jj) {
      bf16x8 p8 = *(const bf16x8*)(pr + jj * 8);
      f32x4 o0, o1;
      o0[0] = bf2f(p8[0]) * rd; o0[1] = bf2f(p8[1]) * rd;
      o0[2] = bf2f(p8[2]) * rd; o0[3] = bf2f(p8[3]) * rd;
      o1[0] = bf2f(p8[4]) * rd; o1[1] = bf2f(p8[5]) * rd;
      o1[2] = bf2f(p8[6]) * rd; o1[3] = bf2f(p8[7]) * rd;
      __builtin_nontemporal_store(o0, (f32x4*)(orow + jj * 8));
      __builtin_nontemporal_store(o1, (f32x4*)(orow + jj * 8 + 4));
    }
  }
  __syncthreads();
  if (w < 2) {
    int rh2 = w;
    int row0e = rq * 32 + rh2 * 16;
    f32x4 rs = part[0][rh2][0][l] + part[0][rh2][1][l];
    f32x4 zs = part[1][rh2][0][l] + part[1][rh2][1][l];
    f32x4 is = part[2][rh2][0][l] + part[2][rh2][1][l];
    f32x4 hs = part[3][rh2][0][l] + part[3][rh2][1][l];
    int col = col0 + lr;
    float bihr = bih[col], bhhr = bhh[col];
    float bihz = bih[kH + col], bhhz = bhh[kH + col];
    float bihn = bih[2 * kH + col], bhhn = bhh[2 * kH + col];
#pragma unroll
    for (int j = 0; j < 4; ++j) {
      int row = row0e + g * 4 + j;
      float r = sigm(rs[j] + bihr + bhhr);
      float z = sigm(zs[j] + bihz + bhhz);
      float nn = tanhf(is[j] + bihn + r * (hs[j] + bhhn));
      float hv = (1.0f - z) * nn + z * hf[row * kH + col];
      hf[row * kH + col] = hv;
      hb_next[row * kH + col] = f2bf(hv);
    }
  }
}

// ---------------- logits v4: global_load_lds-staged wout + GEMM + p=exp + denom ----------------
// grid 512 (V/32 tiles), 256 thr (4 waves 2M x 2N; wave = 64 rows x 16 cols).
// Stage: 32-row wout slice (64 KB contiguous) -> LDS via global_load_lds width=16
// (no VGPR round trip); padded stride 2064 B keeps ds_read_b128 conflict-free and each
// wave's 64 chunks stay inside one row (LDS dest linear per wave, as the DMA requires).
__global__ __launch_bounds__(256, 2) void k_logits(
    const short* __restrict__ h_b, const short* __restrict__ wout_b,
    const float* __restrict__ bout, const float* __restrict__ gum_t,
    short* __restrict__ p_b, float* __restrict__ denom, float* __restrict__ e_f) {
  __shared__ char lds[32 * 2064];  // 66048 B
  __shared__ float ls[2][2][64];
  int tid = threadIdx.x;
  int l = tid & 63, w = tid >> 6;
  int lr = l & 15, g = l >> 4, lk = g * 8;
  int wm = w & 1, wn = w >> 1;
  int col = blockIdx.x * 32 + wn * 16 + lr;
  int mrow0 = wm * 64;
  // ---- stage wout slice first: 4096 16-B chunks via direct global->LDS DMA ----
  {
    const char* src = (const char*)(wout_b + (size_t)blockIdx.x * 32 * kH);
#pragma unroll
    for (int i = 0; i < 16; ++i) {
      int c = tid + i * 256;           // chunk id 0..4095
      int row = c >> 7;
      int within = (c & 127) * 16;
      __builtin_amdgcn_global_load_lds(
          (const __attribute__((address_space(1))) unsigned int*)(src + c * 16),
          (__attribute__((address_space(3))) unsigned int*)(&lds[row * 2064 + within]),
          16, 0, 0);
    }
  }
  int gi = blockIdx.x * 256 + tid;
  if (gi < kB * kE) e_f[gi] = 0.0f;  // zero e accumulator for k_e atomics
  float gmr[16];
#pragma unroll
  for (int mf = 0; mf < 4; ++mf)
#pragma unroll
    for (int j = 0; j < 4; ++j)
      gmr[mf * 4 + j] = __builtin_nontemporal_load(
          &gum_t[(size_t)(mrow0 + mf * 16 + g * 4 + j) * kV + col]);
  float bo = bout[col];
  bf16x8 arg[2][4];
#pragma unroll
  for (int k = 0; k < 2; ++k)
#pragma unroll
    for (int mf = 0; mf < 4; ++mf)
      arg[k][mf] = *(const bf16x8*)&h_b[(mrow0 + mf * 16 + lr) * kH + k * 32 + lk];
  __syncthreads();  // drains vmcnt incl. the LDS DMA
  const char* bbase = &lds[(wn * 16 + lr) * 2064 + lk * 2];
  f32x4 acc[4] = {};
#pragma unroll
  for (int k = 0; k < 32; ++k) {
    bf16x8 b = *(const bf16x8*)(bbase + k * 64);
    acc[0] = MFMA(arg[k & 1][0], b, acc[0]);
    acc[1] = MFMA(arg[k & 1][1], b, acc[1]);
    acc[2] = MFMA(arg[k & 1][2], b, acc[2]);
    acc[3] = MFMA(arg[k & 1][3], b, acc[3]);
    if (k < 30) {
#pragma unroll
      for (int mf = 0; mf < 4; ++mf)
        arg[k & 1][mf] =
            *(const bf16x8*)&h_b[(mrow0 + mf * 16 + lr) * kH + (k + 2) * 32 + lk];
    }
  }
  float p[16];
#pragma unroll
  for (int i = 0; i < 16; ++i) p[i] = __expf(acc[i >> 2][i & 3] + bo + gmr[i]);
#pragma unroll
  for (int i = 0; i < 16; ++i) {
    int rl = (i >> 2) * 16 + g * 4 + (i & 3);
    p_b[(size_t)(mrow0 + rl) * kV + col] = f2bf(p[i]);
  }
#pragma unroll
  for (int i = 0; i < 16; ++i) {
    float s = p[i];
#pragma unroll
    for (int sf = 1; sf < 16; sf <<= 1) s += __shfl_xor(s, sf, 64);
    if (lr == 0) ls[wm][wn][(i >> 2) * 16 + g * 4 + (i & 3)] = s;
  }
  __syncthreads();
  if (tid < 128) {
    int row = tid;
    float sb = ls[row >> 6][0][row & 63] + ls[row >> 6][1][row & 63];
    atomicAdd(&denom[row], sb);
  }
}

// ---------------- e-partial GEMM v3: e_f += x[:, kc] @ emb[:, kc].T (atomic) ----------------
// grid 256 = kc(32 K-chunks of 512) x et(8 E-tiles of 64); 512 thr, waves 2M x 4N.
// emb slice staged to LDS double-buffered per 128-col substep (coalesced row-contiguous
// copies replace 16-line strided gathers); p loads hoisted before MFMA (issue-early).
__global__ __launch_bounds__(512) void k_e(
    const short* __restrict__ p_b, const float* __restrict__ denom,
    const short* __restrict__ emb_b, float* __restrict__ e_f) {
  int tid = threadIdx.x;
  int l = tid & 63, w = tid >> 6;
  int lr = l & 15, g = l >> 4, lk = g * 8;
  int wm = w >> 2, wn = w & 3;
  int kc = blockIdx.x >> 3, et = blockIdx.x & 7;
  int kbase = kc * 512;
  __shared__ float s_rd[kB];
  __shared__ bf16x8 xs8[2048];      // 128 rows x 128 cols bf16, XOR-swizzled (32 KB)
  __shared__ char es[2][64 * 264];  // emb substep buffers, 2 x 16.5 KB
  char* xs = (char*)xs8;
  if (tid < kB) s_rd[tid] = 1.0f / denom[tid];
  __syncthreads();  // s_rd visible to all before prologue staging reads it
  int colg = tid & 15, rrow = tid >> 4;
  // emb stage indexing: 1024 chunks of 16B per substep; thread handles 2
  int ec0 = tid * 2, ec1 = tid * 2 + 1;
  int er0 = ec0 >> 4, ew0 = (ec0 & 15) * 16;
  int er1 = ec1 >> 4, ew1 = (ec1 & 15) * 16;
  const char* esrc0 = (const char*)&emb_b[(size_t)(et * 64 + er0) * kV + kbase] + ew0;
  const char* esrc1 = (const char*)&emb_b[(size_t)(et * 64 + er1) * kV + kbase] + ew1;
  // prologue: stage emb(0) + p(0)
  {
    bf16x8 e0 = *(const bf16x8*)esrc0;
    bf16x8 e1 = *(const bf16x8*)esrc1;
    *(bf16x8*)&es[0][er0 * 264 + ew0] = e0;
    *(bf16x8*)&es[0][er1 * 264 + ew1] = e1;
#pragma unroll
    for (int rr = 0; rr < 4; ++rr) {
      int row = rr * 32 + rrow;
      bf16x8 p8 = *(const bf16x8*)&p_b[(size_t)row * kV + kbase + colg * 8];
      float scl = s_rd[row];
      bf16x8 xv;
#pragma unroll
      for (int i = 0; i < 8; ++i) xv[i] = f2bf(bf2f(p8[i]) * scl);
      unsigned off = (unsigned)(row * 256 + colg * 16) ^ ((row & 7) << 4);
      *(bf16x8*)(xs + off) = xv;
    }
  }
  __syncthreads();
  f32x4 acc[4] = {};
  int ebrow = wn * 16 + lr;
  for (int s = 0; s < 4; ++s) {
    int cur = s & 1;
    // issue next-substep loads early (land during MFMA below)
    bf16x8 ne0, ne1, np[4];
    if (s < 3) {
      ne0 = *(const bf16x8*)(esrc0 + (s + 1) * 256);
      ne1 = *(const bf16x8*)(esrc1 + (s + 1) * 256);
#pragma unroll
      for (int rr = 0; rr < 4; ++rr) {
        int row = rr * 32 + rrow;
        np[rr] = *(const bf16x8*)&p_b[(size_t)row * kV + kbase + (s + 1) * 128 + colg * 8];
      }
    }
    // MFMA substep s: B from es[cur], A from xs
#pragma unroll
    for (int kk = 0; kk < 4; ++kk) {
      bf16x8 b = *(const bf16x8*)&es[cur][ebrow * 264 + kk * 64 + lk * 2];
#pragma unroll
      for (int mf = 0; mf < 4; ++mf) {
        int rowa = wm * 64 + mf * 16 + lr;
        unsigned off = (unsigned)(rowa * 256 + (kk * 32 + lk) * 2) ^ ((rowa & 7) << 4);
        bf16x8 a = *(const bf16x8*)(xs + off);
        acc[mf] = MFMA(a, b, acc[mf]);
      }
    }
    if (s < 3) {
      __syncthreads();  // everyone done reading xs / es[cur] this round
      *(bf16x8*)&es[cur ^ 1][er0 * 264 + ew0] = ne0;
      *(bf16x8*)&es[cur ^ 1][er1 * 264 + ew1] = ne1;
#pragma unroll
      for (int rr = 0; rr < 4; ++rr) {
        int row = rr * 32 + rrow;
        float scl = s_rd[row];
        bf16x8 xv;
#pragma unroll
        for (int i = 0; i < 8; ++i) xv[i] = f2bf(bf2f(np[rr][i]) * scl);
        unsigned off = (unsigned)(row * 256 + colg * 16) ^ ((row & 7) << 4);
        *(bf16x8*)(xs + off) = xv;
      }
      __syncthreads();
    }
  }
#pragma unroll
  for (int mf = 0; mf < 4; ++mf)
#pragma unroll
    for (int j = 0; j < 4; ++j) {
      int row = wm * 64 + mf * 16 + g * 4 + j;
      atomicAdd(&e_f[row * kE + et * 64 + wn * 16 + lr], acc[mf][j]);
    }
}

// ---------------- epilogue: write out for the final step ----------------
__global__ __launch_bounds__(256) void k_out(const short* __restrict__ p_b,
                                             const float* __restrict__ denom,
                                             float* __restrict__ outp) {
  int tid = threadIdx.x, bid = blockIdx.x;
  int r = bid >> 1, halfc = bid & 1;
  float rd = 1.0f / denom[r];
  int coff = halfc * 8192 + tid * 32;
  const short* pr = p_b + (size_t)r * kV + coff;
  float* orow = outp + (size_t)r * (kT * kV) + coff;
#pragma unroll
  for (int jj = 0; jj < 4; ++jj) {
    bf16x8 p8 = *(const bf16x8*)(pr + jj * 8);
    f32x4 o0, o1;
    o0[0] = bf2f(p8[0]) * rd; o0[1] = bf2f(p8[1]) * rd;
    o0[2] = bf2f(p8[2]) * rd; o0[3] = bf2f(p8[3]) * rd;
    o1[0] = bf2f(p8[4]) * rd; o1[1] = bf2f(p8[5]) * rd;
    o1[2] = bf2f(p8[6]) * rd; o1[3] = bf2f(p8[7]) * rd;
    __builtin_nontemporal_store(o0, (f32x4*)(orow + jj * 8));
    __builtin_nontemporal_store(o1, (f32x4*)(orow + jj * 8 + 4));
  }
}

}  // namespace

extern "C" void kernel_launch(void* const* d_in, const int* in_sizes, int n_in,
                              void* d_out, int out_size, void* d_ws, size_t ws_size,
                              hipStream_t stream) {
  const float* img = (const float*)d_in[0];
  const float* aw = (const float*)d_in[1];
  const float* ab = (const float*)d_in[2];
  const float* wih = (const float*)d_in[3];
  const float* whh = (const float*)d_in[4];
  const float* bih = (const float*)d_in[5];
  const float* bhh = (const float*)d_in[6];
  const float* wout = (const float*)d_in[7];
  const float* bout = (const float*)d_in[8];
  const float* emb = (const float*)d_in[9];
  const float* sos = (const float*)d_in[10];
  const float* gum = (const float*)d_in[11];
  float* out = (float*)d_out;
  char* ws = (char*)d_ws;

  short* wout_b = (short*)(ws + 0);            // 33554432
  short* emb_b = (short*)(ws + 33554432);      // 16777216
  short* wih_b = (short*)(ws + 50331648);      // 3145728
  short* whh_b = (short*)(ws + 53477376);      // 6291456
  short* aw_b = (short*)(ws + 59768832);       // 4194304
  short* img_b = (short*)(ws + 63963136);      // 524288
  float* hf = (float*)(ws + 64487424);         // 524288 (fp32 h, in-place)
  short* hb0 = (short*)(ws + 65011712);        // 262144
  short* hb1 = (short*)(ws + 65273856);        // 262144
  short* p_b = (short*)(ws + 65536000);        // 4194304
  float* denoms = (float*)(ws + 69730304);     // 2048 (2 x 256 floats)
  float* e_f = (float*)(ws + 69732352);        // 262144 (fp32 e accumulator)

  short* hb[2] = {hb0, hb1};

  k_convert<<<2048, 256, 0, stream>>>(wout, emb, wih, whh, aw, img, sos, wout_b, emb_b,
                                      wih_b, whh_b, aw_b, img_b, e_f);
  k_h0<<<64, 256, 0, stream>>>(img_b, aw_b, ab, hf, hb[0]);
  for (int t = 0; t < kT; ++t) {
    int rp = t & 1, wp = rp ^ 1;
    float* denomC = denoms + (t & 1) * 256;
    float* denomP = denoms + ((t & 1) ^ 1) * 256;
    float* out_prev = (t == 0) ? nullptr : out + (size_t)(t - 1) * kV;
    k_gru<<<256, 512, 0, stream>>>(e_f, hb[rp], hf, wih_b, whh_b, bih, bhh, hb[wp],
                                   denomC, p_b, denomP, out_prev);
    k_logits<<<512, 256, 0, stream>>>(hb[wp], wout_b, bout, gum + (size_t)t * kB * kV,
                                      p_b, denomC, e_f);
    k_e<<<256, 512, 0, stream>>>(p_b, denomC, emb_b, e_f);
  }
  k_out<<<256, 256, 0, stream>>>(p_b, denoms + 256, out + (size_t)(kT - 1) * kV);
}